// Round 14
// baseline (218.419 us; speedup 1.0000x reference)
//
#include <hip/hip_runtime.h>
#include <math.h>

#define NROWS 16384
#define DDIM  2048
#define EEXP  64
#define RB    32                 // rows per block
#define KSPLIT 4                 // K-slices -> grid 2048, short blocks, high churn
#define CHB    8                 // chunks (KC=64) per block = 512 k
#define CHSTRIDE 24576           // ws bytes per chunk: 8 pages * 3 lvl * 1KB
#define PART_OFF (1u << 20)      // fp32 partials at d_ws + 1 MB (16 MB)

typedef short        bf16x8 __attribute__((ext_vector_type(8)));
typedef float        f32x16 __attribute__((ext_vector_type(16)));
typedef float        f32x4  __attribute__((ext_vector_type(4)));
typedef unsigned int u32x4  __attribute__((ext_vector_type(4)));

union V4 { u32x4 u; bf16x8 s; };

// Truncating 3-way bf16 split: f = X0 + X1 + X2 + eps, |eps| <= 2^-24 |f|
static __device__ __forceinline__ void split3x2(float f0, float f1,
                                                unsigned int &p0, unsigned int &p1,
                                                unsigned int &p2) {
    unsigned int a0 = __float_as_uint(f0), b0 = __float_as_uint(f1);
    unsigned int ah = a0 & 0xffff0000u,   bh = b0 & 0xffff0000u;
    float fa1 = f0 - __uint_as_float(ah);
    float fb1 = f1 - __uint_as_float(bh);
    unsigned int a1 = __float_as_uint(fa1), b1 = __float_as_uint(fb1);
    unsigned int am = a1 & 0xffff0000u,     bm = b1 & 0xffff0000u;
    float fa2 = fa1 - __uint_as_float(am);
    float fb2 = fb1 - __uint_as_float(bm);
    p0 = (a0 >> 16) | bh;
    p1 = (a1 >> 16) | bm;
    p2 = (__float_as_uint(fa2) >> 16) | (__float_as_uint(fb2) & 0xffff0000u);
}

static __device__ __forceinline__ void cvt8(f32x4 u, f32x4 v, V4 &q0, V4 &q1, V4 &q2) {
    unsigned int a, b, c;
    split3x2(u[0], u[1], a, b, c); q0.u[0] = a; q1.u[0] = b; q2.u[0] = c;
    split3x2(u[2], u[3], a, b, c); q0.u[1] = a; q1.u[1] = b; q2.u[1] = c;
    split3x2(v[0], v[1], a, b, c); q0.u[2] = a; q1.u[2] = b; q2.u[2] = c;
    split3x2(v[2], v[3], a, b, c); q0.u[3] = a; q1.u[3] = b; q2.u[3] = c;
}

#define MM(ACC, A, B) ACC = __builtin_amdgcn_mfma_f32_32x32x16_bf16((A), (B), ACC, 0, 0, 0)

// ---- prep: W -> per-(chunk,kg,et,lvl) 1KB pages, lane-contiguous (R9-identical) ----
__global__ __launch_bounds__(256)
void wsplit_kernel(const float* __restrict__ W, unsigned char* __restrict__ ws) {
    const int t  = blockIdx.x * 256 + threadIdx.x;
    const int e  = t & 63;
    const int ko = t >> 6;
    const int k0 = ko * 8;
    f32x4 u, v;
#pragma unroll
    for (int j = 0; j < 4; ++j) u[j] = W[(size_t)(k0 + j) * EEXP + e];
#pragma unroll
    for (int j = 0; j < 4; ++j) v[j] = W[(size_t)(k0 + 4 + j) * EEXP + e];
    V4 q0, q1, q2;
    cvt8(u, v, q0, q1, q2);
    const int c  = ko >> 3;
    const int kg = (ko >> 1) & 3;
    const int h  = ko & 1;
    const int et = e >> 5;
    const int ln = h * 32 + (e & 31);
    unsigned char* d = ws + (size_t)((c * 8 + kg * 2 + et) * 3) * 1024 + ln * 16;
    *(u32x4*)(d +    0) = q0.u;
    *(u32x4*)(d + 1024) = q1.u;
    *(u32x4*)(d + 2048) = q2.u;
}

// ---- main: one (row-group, K-slice) per block; fp32 partial to d_ws ----
__global__ __launch_bounds__(512, 3)
void matmul_kernel(const float* __restrict__ x,
                   const unsigned char* __restrict__ wsplit,
                   float* __restrict__ part) {
    __shared__ __align__(16) float smem[8192];  // [2][32][64] x-stage; 32KB reduce overlay

    const int tid  = threadIdx.x;
    const int lane = tid & 63;
    const int w    = __builtin_amdgcn_readfirstlane(tid >> 6);
    const int kg   = w & 3;
    const int et   = w >> 2;
    const int l31  = lane & 31;
    const int h    = lane >> 5;

    // bijective XCD swizzle over 2048 blocks; decompose -> (row-group, k-slice)
    const int bid  = blockIdx.x;
    const int bswz = (bid & 7) * ((int)gridDim.x >> 3) + (bid >> 3);
    const int rg   = bswz >> 2;
    const int ks   = bswz & 3;
    const int row0 = rg * RB;
    const int c0   = ks * CHB;

    // x staging (gload_lds width=16): dest = wave-uniform base + lane*16 (linear);
    // source 16B-slot pre-XORed by (row&7) -> R9-identical LDS image.
    const int strow = tid >> 4;                       // 0..31
    const int sslot = (tid & 15) ^ (strow & 7);
    const float* xsrc = x + (size_t)(row0 + strow) * DDIM + c0 * 64 + sslot * 4;
    float* sdst = smem + strow * 64 + (tid & 15) * 4;

#define GLL(S, BUF)                                                           \
    __builtin_amdgcn_global_load_lds(                                         \
        (const __attribute__((address_space(1))) void*)(xsrc + (S) * 64),     \
        (__attribute__((address_space(3))) void*)(sdst + (BUF) * 4096),       \
        16, 0, 0);

    // B stream: 1KB lane-contiguous pages (R9 layout), this block's k-slice
    const unsigned char* wq = wsplit + (size_t)((kg * 2 + et) * 3) * 1024
                            + lane * 16 + (size_t)c0 * CHSTRIDE;

    // fragment read offsets (XOR-deswizzled)
    const int bb = kg * 4 + h * 2;
    const int xr = l31 & 7;
    const int loOff = l31 * 64 + (((bb    ) ^ xr) << 2);
    const int hiOff = l31 * 64 + (((bb + 1) ^ xr) << 2);

    f32x16 accA, accB;
#pragma unroll
    for (int i = 0; i < 16; ++i) { accA[i] = 0.f; accB[i] = 0.f; }

    GLL(0, 0)
    __syncthreads();

#pragma unroll 1
    for (int s = 0; s < CHB; ++s) {
        const int buf = s & 1;
        if (s + 1 < CHB) { GLL(s + 1, buf ^ 1) }   // fire-and-forget next stage

        const float* xb = smem + buf * 4096;
        f32x4 lo = *(const f32x4*)(xb + loOff);
        f32x4 hi = *(const f32x4*)(xb + hiOff);
        const unsigned char* q = wq + (size_t)s * CHSTRIDE;
        V4 b0, b1, b2;
        b0.u = *(const u32x4*)(q);
        b1.u = *(const u32x4*)(q + 1024);
        b2.u = *(const u32x4*)(q + 2048);
        V4 a0, a1, a2;
        cvt8(lo, hi, a0, a1, a2);
        MM(accA, a0.s, b0.s); MM(accB, a0.s, b1.s); MM(accA, a1.s, b0.s);
        MM(accB, a0.s, b2.s); MM(accA, a1.s, b1.s); MM(accB, a2.s, b0.s);

        __syncthreads();   // drains next-stage DMA; buf swap safe
    }

    // in-block kg-reduce (LDS overlay), then 8KB coalesced partial to d_ws
    // C/D layout: col = lane&31, row = (reg&3) + 8*(reg>>2) + 4*(lane>>5)
#pragma unroll
    for (int r = 0; r < 16; ++r) {
        const int rowl = (r & 3) + 8 * (r >> 2) + 4 * h;
        smem[kg * 2048 + rowl * 64 + et * 32 + l31] = accA[r] + accB[r];
    }
    __syncthreads();
    f32x4 s0 = *(const f32x4*)(smem + tid * 4);
    f32x4 s1 = *(const f32x4*)(smem + 2048 + tid * 4);
    f32x4 s2 = *(const f32x4*)(smem + 4096 + tid * 4);
    f32x4 s3 = *(const f32x4*)(smem + 6144 + tid * 4);
    f32x4 t;
#pragma unroll
    for (int i = 0; i < 4; ++i) t[i] = s0[i] + s1[i] + s2[i] + s3[i];
    *(f32x4*)(part + (size_t)(rg * 4 + ks) * 2048 + tid * 4) = t;
}

// ---- finish: sum 4 k-slice partials + bias, softmax + top2 (proven code) ----
__global__ __launch_bounds__(512)
void finish_kernel(const float* __restrict__ part,
                   const float* __restrict__ bias_v,
                   float* __restrict__ mask_out,
                   float* __restrict__ idx_out) {
    const int tid  = threadIdx.x;
    const int lane = tid & 63;
    const int w    = __builtin_amdgcn_readfirstlane(tid >> 6);
    const int b    = blockIdx.x;                  // 512 blocks x 32 rows
    const float bias = bias_v[lane];
    const float* p0 = part + (size_t)b * 4 * 2048;

#pragma unroll
    for (int rr = 0; rr < 4; ++rr) {
        const int rl  = w * 4 + rr;
        const int row = b * 32 + rl;
        float logit = bias + p0[rl * 64 + lane]
                           + p0[2048 + rl * 64 + lane]
                           + p0[4096 + rl * 64 + lane]
                           + p0[6144 + rl * 64 + lane];

        float m = logit;
#pragma unroll
        for (int off = 32; off >= 1; off >>= 1) m = fmaxf(m, __shfl_xor(m, off));
        float ex = __expf(logit - m);
        float s = ex;
#pragma unroll
        for (int off = 32; off >= 1; off >>= 1) s += __shfl_xor(s, off);
        float gate = ex / s;

        float v1 = logit; int i1 = lane;
#pragma unroll
        for (int off = 32; off >= 1; off >>= 1) {
            float ov = __shfl_xor(v1, off);
            int   oi = __shfl_xor(i1, off);
            if (ov > v1 || (ov == v1 && oi < i1)) { v1 = ov; i1 = oi; }
        }
        float v2 = (lane == i1) ? -INFINITY : logit; int i2 = lane;
#pragma unroll
        for (int off = 32; off >= 1; off >>= 1) {
            float ov = __shfl_xor(v2, off);
            int   oi = __shfl_xor(i2, off);
            if (ov > v2 || (ov == v2 && oi < i2)) { v2 = ov; i2 = oi; }
        }

        float outv = (lane == i1 || lane == i2) ? gate : 0.0f;
        mask_out[(size_t)row * EEXP + lane] = outv;
        if (lane == 0) {
            idx_out[row * 2 + 0] = (float)i1;
            idx_out[row * 2 + 1] = (float)i2;
        }
    }
}

extern "C" void kernel_launch(void* const* d_in, const int* in_sizes, int n_in,
                              void* d_out, int out_size, void* d_ws, size_t ws_size,
                              hipStream_t stream) {
    const float* x = (const float*)d_in[0];
    const float* W = (const float*)d_in[1];
    const float* b = (const float*)d_in[2];
    float* mask_out = (float*)d_out;
    float* idx_out  = mask_out + (size_t)NROWS * EEXP;
    unsigned char* ws = (unsigned char*)d_ws;     // 768 KB wsplit + 16 MB partials
    float* part = (float*)(ws + PART_OFF);

    wsplit_kernel<<<dim3(64), dim3(256), 0, stream>>>(W, ws);
    matmul_kernel<<<dim3((NROWS / RB) * KSPLIT), dim3(512), 0, stream>>>(x, ws, part);
    finish_kernel<<<dim3(NROWS / RB), dim3(512), 0, stream>>>(part, b, mask_out, idx_out);
}